// Round 4
// baseline (600.291 us; speedup 1.0000x reference)
//
#include <hip/hip_runtime.h>

// SemanticCaps dynamic routing, fp32. B=128, J=10, K=1152, M=16, I=8.
// R8: R5 split structure (best: 144 µs) + atomic-S reduction. sp tensor
// eliminated: iter blocks atomicAdd their 16 per-thread partials into
// S[j][b][m] (80 KB, L2-resident); squash folds into the NEXT pass as a
// pure per-thread epilogue (each thread owns a full m-row -> no shuffles).
// 7 dispatches -> 5. Iter core (scalar-path Ws, per-k earr softmax) is
// unchanged from R5. Cooperative grid.sync abandoned (R3: ~55 µs/sync,
// 192 MB spin-fetch traffic).
// b-logit algebra: b after t iters = u.(v0+..+v_{t-1}) (b starts at 0).
//
// ws (floats): xT[9216*128] S0[20480] S1[20480] S2[20480]

#define B_ 128
#define J_ 10
#define K_ 1152
#define M_ 16
#define I_ 8
#define KT 9
#define NKT (K_ / KT)       // 128 k-tiles
#define RW (K_ * I_)        // 9216 rows of xT
#define SVEC (J_ * B_ * M_) // 20480 floats per S accumulator

// ---------- transpose x[b][k][i] -> xT[k*8+i][b]; also zero S0/S1/S2 --------
__global__ __launch_bounds__(256)
void xpose_kernel(const float* __restrict__ x, float* __restrict__ xT,
                  float* __restrict__ S012) {
    __shared__ float tile[64 * 65];
    const int t = threadIdx.x;
    // zero the three poisoned S accumulators (288 blocks x 256 thr >= 61440)
    const int gz = (blockIdx.y * gridDim.x + blockIdx.x) * 256 + t;
    if (gz < 3 * SVEC) S012[gz] = 0.f;
    const int r0 = blockIdx.x * 64, b0 = blockIdx.y * 64;
    const int hi = t >> 6, lo = t & 63;
#pragma unroll 4
    for (int c = 0; c < 16; ++c) {
        const int bb = c * 4 + hi;
        tile[lo * 65 + bb] = x[(size_t)(b0 + bb) * RW + r0 + lo];
    }
    __syncthreads();
#pragma unroll 4
    for (int c = 0; c < 16; ++c) {
        const int r = c * 4 + hi;
        xT[(size_t)(r0 + r) * B_ + b0 + lo] = tile[r * 65 + lo];
    }
}

// ---------- per-thread squash of one S row (thread owns all 16 m) -----------
__device__ __forceinline__ void row_squash(const float* __restrict__ Srow,
                                           float scale, float* __restrict__ v,
                                           bool add) {
    float a[M_];
    const float4* p = (const float4*)Srow;
#pragma unroll
    for (int q = 0; q < 4; ++q) {
        const float4 w = p[q];
        a[4*q] = w.x * scale; a[4*q+1] = w.y * scale;
        a[4*q+2] = w.z * scale; a[4*q+3] = w.w * scale;
    }
    float sq = 0.f;
#pragma unroll
    for (int m = 0; m < M_; ++m) sq += a[m] * a[m];
    const float n = sqrtf(sq);
    const float f = n / (1.f + sq);          // squash(s) = s * n/(1+|s|^2)
#pragma unroll
    for (int m = 0; m < M_; ++m) {
        if (add) v[m] += a[m] * f; else v[m] = a[m] * f;
    }
}

// ---------- routing pass -----------------------------------------------------
// MODE 0: c == 1 (iteration 0; 0.1 deferred to S0 consumers)
// MODE 1: vin = squash(0.1*S0)
// MODE 2: vin = squash(0.1*S0) + squash(S1)
// Wave = output capsule j (10 waves), lane = batch b (64). Ws via the
// SCALAR path (wave-uniform address after readfirstlane(j)). Epilogue:
// 16 atomicAdds into Sout[j][b][m] (device-scope, L2-resident).
template <int MODE>
__global__ __launch_bounds__(640)
void iter_kernel(const float* __restrict__ xT, const float* __restrict__ Ws,
                 const float* __restrict__ S0, const float* __restrict__ S1,
                 float* __restrict__ Sout) {
    __shared__ float earr[2][J_ * 64];
    const int t  = threadIdx.x;
    const int bl = t & 63;
    const int j  = __builtin_amdgcn_readfirstlane(t >> 6);  // wave-uniform j
    const int kt = blockIdx.x, bg = blockIdx.y;
    const int b  = bg * 64 + bl;

    float v[M_], s[M_];
#pragma unroll
    for (int m = 0; m < M_; ++m) s[m] = 0.f;
    if (MODE >= 1) {
        row_squash(S0 + ((size_t)j * B_ + b) * M_, 0.1f, v, false);
        if (MODE == 2)
            row_squash(S1 + ((size_t)j * B_ + b) * M_, 1.0f, v, true);
    }

    for (int kk = 0; kk < KT; ++kk) {
        const int k = kt * KT + kk;
        float xr[I_];
#pragma unroll
        for (int i = 0; i < I_; ++i) xr[i] = xT[(size_t)(k * I_ + i) * B_ + b];

        const float* w = Ws + ((size_t)j * K_ + k) * (M_ * I_);  // uniform -> s_load
        float u[M_];
#pragma unroll
        for (int m = 0; m < M_; ++m) {
            float a = 0.f;
#pragma unroll
            for (int i = 0; i < I_; ++i) a += w[m * I_ + i] * xr[i];
            u[m] = a;
        }

        if (MODE >= 1) {
            float lg = 0.f;
#pragma unroll
            for (int m = 0; m < M_; ++m) lg += u[m] * v[m];
            const float e = __expf(lg);
            earr[kk & 1][j * 64 + bl] = e;
            __syncthreads();   // one barrier/k; ping-pong makes reuse race-free
            float den = 0.f;
#pragma unroll
            for (int jj = 0; jj < J_; ++jj) den += earr[kk & 1][jj * 64 + bl];
            const float c = __fdividef(e, den);
#pragma unroll
            for (int m = 0; m < M_; ++m) s[m] += c * u[m];
        } else {
#pragma unroll
            for (int m = 0; m < M_; ++m) s[m] += u[m];
        }
    }

    float* o = Sout + ((size_t)j * B_ + b) * M_;
#pragma unroll
    for (int m = 0; m < M_; ++m) atomicAdd(o + m, s[m]);
}

// ---------- finish: out = squash(S2), standard [b][j][m] layout --------------
__global__ __launch_bounds__(256)
void finish_kernel(const float* __restrict__ S2, float* __restrict__ out) {
    const int g = blockIdx.x * 256 + threadIdx.x;   // g = (j*128+b)*16+m
    const int m = g & 15;
    const int b = (g >> 4) & 127;
    const int j = g >> 11;
    const float S = S2[g];
    float sq = S * S;
    sq += __shfl_xor(sq, 1, 64);
    sq += __shfl_xor(sq, 2, 64);
    sq += __shfl_xor(sq, 4, 64);
    sq += __shfl_xor(sq, 8, 64);          // sum over m within 16-lane group
    const float n = sqrtf(sq);
    out[((size_t)b * J_ + j) * M_ + m] = S * (n / (1.f + sq));
}

extern "C" void kernel_launch(void* const* d_in, const int* in_sizes, int n_in,
                              void* d_out, int out_size, void* d_ws, size_t ws_size,
                              hipStream_t stream) {
    const float* x  = (const float*)d_in[0];   // [128][1152][8]
    const float* Ws = (const float*)d_in[1];   // [10][1152][16][8]
    float* out = (float*)d_out;                // [128][10][16]

    float* xT = (float*)d_ws;                  // 1,179,648 floats
    float* S0 = xT + (size_t)RW * B_;          // 20,480
    float* S1 = S0 + SVEC;                     // 20,480
    float* S2 = S1 + SVEC;                     // 20,480

    xpose_kernel<<<dim3(RW / 64, 2), 256, 0, stream>>>(x, xT, S0);

    iter_kernel<0><<<dim3(NKT, 2), 640, 0, stream>>>(xT, Ws, nullptr, nullptr, S0);
    iter_kernel<1><<<dim3(NKT, 2), 640, 0, stream>>>(xT, Ws, S0, nullptr, S1);
    iter_kernel<2><<<dim3(NKT, 2), 640, 0, stream>>>(xT, Ws, S0, S1, S2);

    finish_kernel<<<80, 256, 0, stream>>>(S2, out);
}

// Round 5
// 137.632 us; speedup vs baseline: 4.3616x; 4.3616x over previous
//
#include <hip/hip_runtime.h>

// SemanticCaps dynamic routing, fp32. B=128, J=10, K=1152, M=16, I=8.
// R9 = R5 (best proven: 144 µs) + two targeted cuts:
//  (a) squash fold parallelized (320 blocks, 4-wave split per 64 outputs) —
//      R5's 80-block squash was ~11 µs of serial 80KB-stride L3 latency
//      chains per dispatch (384 loads/thread, unroll-8).
//  (b) xpose fused into iter: each block LDS-transposes its own 18 KB
//      x-tile; xpose dispatch and xT tensor eliminated (7 -> 6 dispatches).
// Iter core (scalar-path Ws via readfirstlane(j), per-k earr ping-pong
// softmax) byte-identical to R5. Atomics (R8: fabric-level, 84 MB/pass) and
// grid.sync (R3: ~55 µs/sync) both ruled out by measurement.
// b-logit algebra: b after t iters = u.(v0+..+v_{t-1}) (b starts at 0).
//
// ws (floats): sp[128*10*128*16] v0T[20480] vsumT[20480]

#define B_ 128
#define J_ 10
#define K_ 1152
#define M_ 16
#define I_ 8
#define KT 9
#define NKT (K_ / KT)        // 128 k-tiles
#define RW (K_ * I_)         // 9216 floats per x batch-row
#define SVEC (J_ * B_ * M_)  // 20480 floats per fold-slice of sp

// ---------- routing pass -----------------------------------------------------
// MODE 0: c == 1 (iteration 0; 0.1 folded into squash<0>)
// MODE 1: c = softmax_j(u . vin);  s = sum_k c*u (u stays in registers)
// Wave = output capsule j (10 waves), lane = batch b (64). Block stages its
// own 72x64 x-tile via LDS transpose (replaces the xpose kernel + xT tensor).
template <int MODE>
__global__ __launch_bounds__(640)
void iter_kernel(const float* __restrict__ x, const float* __restrict__ Ws,
                 const float* __restrict__ vinT, float* __restrict__ sp) {
    __shared__ float xtile[KT * I_ * 64];    // 72 rows x 64 b = 18 KB
    __shared__ float earr[2][J_ * 64];
    const int t  = threadIdx.x;
    const int bl = t & 63;
    const int j  = __builtin_amdgcn_readfirstlane(t >> 6);  // wave-uniform j
    const int kt = blockIdx.x, bg = blockIdx.y;
    const int b  = bg * 64 + bl;

    // ---- stage + transpose x[b0..b0+63][kt*72 .. +72) -> xtile[f][bb] ------
    {
        const float4* x4 = (const float4*)x;          // row stride RW/4 = 2304
        for (int idx = t; idx < 64 * 18; idx += 640) {
            const int bb = idx / 18, q = idx % 18;    // q = float4 within row
            const float4 w = x4[(size_t)(bg * 64 + bb) * (RW / 4) + kt * 18 + q];
            xtile[(q * 4 + 0) * 64 + bb] = w.x;
            xtile[(q * 4 + 1) * 64 + bb] = w.y;
            xtile[(q * 4 + 2) * 64 + bb] = w.z;
            xtile[(q * 4 + 3) * 64 + bb] = w.w;
        }
    }

    float v[M_], s[M_];
#pragma unroll
    for (int m = 0; m < M_; ++m) s[m] = 0.f;
    if (MODE == 1) {
        const float4* vp = (const float4*)(vinT + ((size_t)j * B_ + b) * M_);
#pragma unroll
        for (int q = 0; q < 4; ++q) {
            const float4 w = vp[q];
            v[4*q] = w.x; v[4*q+1] = w.y; v[4*q+2] = w.z; v[4*q+3] = w.w;
        }
    }
    __syncthreads();   // x-tile ready

    for (int kk = 0; kk < KT; ++kk) {
        float xr[I_];
#pragma unroll
        for (int i = 0; i < I_; ++i) xr[i] = xtile[(kk * I_ + i) * 64 + bl];

        const float* w = Ws + ((size_t)j * K_ + kt * KT + kk) * (M_ * I_);  // uniform -> s_load
        float u[M_];
#pragma unroll
        for (int m = 0; m < M_; ++m) {
            float a = 0.f;
#pragma unroll
            for (int i = 0; i < I_; ++i) a += w[m * I_ + i] * xr[i];
            u[m] = a;
        }

        if (MODE == 1) {
            float lg = 0.f;
#pragma unroll
            for (int m = 0; m < M_; ++m) lg += u[m] * v[m];
            const float e = __expf(lg);
            earr[kk & 1][j * 64 + bl] = e;
            __syncthreads();   // one barrier/k; ping-pong makes reuse race-free
            float den = 0.f;
#pragma unroll
            for (int jj = 0; jj < J_; ++jj) den += earr[kk & 1][jj * 64 + bl];
            const float c = __fdividef(e, den);
#pragma unroll
            for (int m = 0; m < M_; ++m) s[m] += c * u[m];
        } else {
#pragma unroll
            for (int m = 0; m < M_; ++m) s[m] += u[m];
        }
    }

    float4* o = (float4*)(sp + (((size_t)kt * J_ + j) * B_ + b) * M_);
#pragma unroll
    for (int q = 0; q < 4; ++q) {
        float4 w;
        w.x = s[4*q]; w.y = s[4*q+1]; w.z = s[4*q+2]; w.w = s[4*q+3];
        o[q] = w;
    }
}

// ---------- squash: parallel fold of 128 tile-partials, emit v ---------------
// 320 blocks x 256 thr; 4 waves each fold 32 slices for 64 outputs, LDS fold,
// wave 0 does the m-shuffle norm + emit.
// SM 0: v0T = squash(0.1*S)  SM 1: vsumT = v0T + squash(S)  SM 2: out = squash(S)
template <int SM>
__global__ __launch_bounds__(256)
void squash_kernel(const float* __restrict__ sp, const float* __restrict__ v0T,
                   float* __restrict__ dst) {
    __shared__ float red[4][64];
    const int t  = threadIdx.x;
    const int l  = t & 63;
    const int wv = t >> 6;
    const int g  = blockIdx.x * 64 + l;   // g = (j*128+b)*16+m
    const int m = g & 15;
    const int b = (g >> 4) & 127;
    const int j = g >> 11;
    const float* p = sp + (size_t)((j * B_ + b) * M_ + m);
    float S = 0.f;
#pragma unroll 8
    for (int tt = wv * (NKT / 4); tt < (wv + 1) * (NKT / 4); ++tt)
        S += p[(size_t)tt * SVEC];
    red[wv][l] = S;
    __syncthreads();
    if (wv == 0) {
        S = red[0][l] + red[1][l] + red[2][l] + red[3][l];
        if (SM == 0) S *= 0.1f;
        float sq = S * S;
        sq += __shfl_xor(sq, 1, 64);
        sq += __shfl_xor(sq, 2, 64);
        sq += __shfl_xor(sq, 4, 64);
        sq += __shfl_xor(sq, 8, 64);      // sum over m within 16-lane group
        const float n = sqrtf(sq);
        float v = S * (n / (1.f + sq));
        if (SM == 1) v += v0T[g];
        if (SM == 2) dst[((size_t)b * J_ + j) * M_ + m] = v;   // standard [b][j][m]
        else         dst[g] = v;                                // vT layout
    }
}

extern "C" void kernel_launch(void* const* d_in, const int* in_sizes, int n_in,
                              void* d_out, int out_size, void* d_ws, size_t ws_size,
                              hipStream_t stream) {
    const float* x  = (const float*)d_in[0];   // [128][1152][8]
    const float* Ws = (const float*)d_in[1];   // [10][1152][16][8]
    float* out = (float*)d_out;                // [128][10][16]

    float* sp    = (float*)d_ws;                           // 2,621,440 floats
    float* v0T   = sp + (size_t)NKT * SVEC;                //    20,480
    float* vsumT = v0T + SVEC;                             //    20,480

    iter_kernel<0><<<dim3(NKT, 2), 640, 0, stream>>>(x, Ws, nullptr, sp);
    squash_kernel<0><<<320, 256, 0, stream>>>(sp, nullptr, v0T);

    iter_kernel<1><<<dim3(NKT, 2), 640, 0, stream>>>(x, Ws, v0T, sp);
    squash_kernel<1><<<320, 256, 0, stream>>>(sp, v0T, vsumT);

    iter_kernel<1><<<dim3(NKT, 2), 640, 0, stream>>>(x, Ws, vsumT, sp);
    squash_kernel<2><<<320, 256, 0, stream>>>(sp, nullptr, out);
}